// Round 2
// 299.495 us; speedup vs baseline: 1.0347x; 1.0347x over previous
//
#include <hip/hip_runtime.h>

// Problem constants (B=32, T=4096, D=256, A=128, window=64)
#define TT 4096
#define DD 256
#define AA 128
#define WIN 64

typedef short bf16x8 __attribute__((ext_vector_type(8)));
typedef float f32x4 __attribute__((ext_vector_type(4)));
typedef unsigned int u32x4 __attribute__((ext_vector_type(4)));

__device__ __forceinline__ unsigned short f2bf(float f) {
    unsigned int u = __builtin_bit_cast(unsigned int, f);
    u += 0x7FFFu + ((u >> 16) & 1u);   // RTNE
    return (unsigned short)(u >> 16);
}

// packed f32x2 -> bf16x2 (RTNE), element 0 = lo
__device__ __forceinline__ unsigned int cvt_pk_bf16(float lo, float hi) {
    unsigned int r;
    asm("v_cvt_pk_bf16_f32 %0, %1, %2" : "=v"(r) : "v"(lo), "v"(hi));
    return r;
}

// ---------------- prep: Wp fp32 -> bf16 (64 KiB, L2-resident) ----------------
__global__ __launch_bounds__(256) void prep_wp(const float* __restrict__ Wp,
                                               unsigned short* __restrict__ wpb) {
    int i = blockIdx.x * 256 + threadIdx.x;   // 32768 total
    wpb[i] = f2bf(Wp[i]);
}

// ---------------- gate: g = sigmoid(Wg . tanh(x Wp^T + bp)) ------------------
// v2: fp32 LDS staging via global_load_lds (fire-and-forget, dwordx4),
// double-buffered 32-row subtiles, XOR-swizzled (pre-swizzled global source,
// linear LDS dest, same XOR on ds_read). bf16 conversion at fragment read via
// v_cvt_pk_bf16_f32. Block = 256 thr (4 waves), wave owns 32 n-cols.
#define RTILE 128
#define SROWS 32
#define NSUB  (RTILE / SROWS)   // 4

__global__ __launch_bounds__(256, 2) void gate_kernel(
        const float* __restrict__ x, const unsigned short* __restrict__ wpb,
        const float* __restrict__ bp, const float* __restrict__ Wg,
        float* __restrict__ g) {
    __shared__ __align__(16) float xs[2][SROWS * DD];   // 2 x 32 KiB fp32
    __shared__ float psum[4][SROWS];
    const int tid  = threadIdx.x;
    const int lane = tid & 63;
    const int wave = tid >> 6;
    const int quad = lane >> 4;
    const int nrow = lane & 15;
    const int sw   = nrow & 7;          // row&7 == nrow&7 (mt*16 ≡ 0 mod 8)
    const long row0 = (long)blockIdx.x * RTILE;
    const float* xbase = x + row0 * DD;

    // B fragments: wave covers n in [wave*32, wave*32+32)
    bf16x8 bfrag[2][8];
    float bpv[2], wgv[2];
#pragma unroll
    for (int nt = 0; nt < 2; ++nt) {
        int n = wave * 32 + nt * 16 + nrow;
        bpv[nt] = bp[n];
        wgv[nt] = Wg[n];
#pragma unroll
        for (int k0 = 0; k0 < 8; ++k0)
            bfrag[nt][k0] = *reinterpret_cast<const bf16x8*>(
                wpb + n * DD + k0 * 32 + quad * 8);
    }

    // stage one 32-row subtile: 8 global_load_lds dwordx4 per wave.
    // LDS dest is linear (row r, granule lane); global source granule is
    // lane^(r&7), so a later read of granule gidx comes from slot gidx^(r&7).
    auto stage = [&](int nb, int s) {
        const float* src = xbase + (long)s * SROWS * DD;
#pragma unroll
        for (int j = 0; j < 8; ++j) {
            int r = wave * 8 + j;
            const float* gp = src + r * DD + ((lane ^ (r & 7)) << 2);
            __builtin_amdgcn_global_load_lds(
                (const __attribute__((address_space(1))) void*)gp,
                (__attribute__((address_space(3))) void*)&xs[nb][r * DD],
                16, 0, 0);
        }
    };

    stage(0, 0);
    __syncthreads();   // drains vmcnt -> buf0 staged & visible

    for (int s = 0; s < NSUB; ++s) {
        if (s + 1 < NSUB) stage((s + 1) & 1, s + 1);   // prefetch next subtile
        const int cur = s & 1;

        f32x4 acc[2][2];
#pragma unroll
        for (int mt = 0; mt < 2; ++mt)
#pragma unroll
            for (int nt = 0; nt < 2; ++nt)
                acc[mt][nt] = (f32x4){0.f, 0.f, 0.f, 0.f};

#pragma unroll
        for (int k0 = 0; k0 < 8; ++k0) {
#pragma unroll
            for (int mt = 0; mt < 2; ++mt) {
                const float* rowp = &xs[cur][(mt * 16 + nrow) * DD];
                const int gidx = quad * 2 + k0 * 8;
                float4 f0 = *reinterpret_cast<const float4*>(rowp + (((gidx)     ^ sw) << 2));
                float4 f1 = *reinterpret_cast<const float4*>(rowp + (((gidx + 1) ^ sw) << 2));
                u32x4 w;
                w.x = cvt_pk_bf16(f0.x, f0.y);
                w.y = cvt_pk_bf16(f0.z, f0.w);
                w.z = cvt_pk_bf16(f1.x, f1.y);
                w.w = cvt_pk_bf16(f1.z, f1.w);
                bf16x8 af = __builtin_bit_cast(bf16x8, w);
                acc[mt][0] = __builtin_amdgcn_mfma_f32_16x16x32_bf16(af, bfrag[0][k0], acc[mt][0], 0, 0, 0);
                acc[mt][1] = __builtin_amdgcn_mfma_f32_16x16x32_bf16(af, bfrag[1][k0], acc[mt][1], 0, 0, 0);
            }
        }

        // epilogue: tanh -> *Wg -> partial row sums (this wave's 32 n-cols)
        float p[2][4];
#pragma unroll
        for (int mt = 0; mt < 2; ++mt)
#pragma unroll
            for (int r = 0; r < 4; ++r) p[mt][r] = 0.f;
#pragma unroll
        for (int nt = 0; nt < 2; ++nt) {
#pragma unroll
            for (int mt = 0; mt < 2; ++mt) {
#pragma unroll
                for (int r = 0; r < 4; ++r) {
                    float pre = acc[mt][nt][r] + bpv[nt];
                    float e  = __expf(2.0f * pre);
                    float th = 1.0f - 2.0f * __builtin_amdgcn_rcpf(e + 1.0f);
                    p[mt][r] += th * wgv[nt];
                }
            }
        }
        // reduce over the 16 nrow lanes (lane bits 0..3)
#pragma unroll
        for (int off = 1; off <= 8; off <<= 1)
#pragma unroll
            for (int mt = 0; mt < 2; ++mt)
#pragma unroll
                for (int r = 0; r < 4; ++r)
                    p[mt][r] += __shfl_xor(p[mt][r], off, 64);
        if (nrow == 0) {
#pragma unroll
            for (int mt = 0; mt < 2; ++mt)
#pragma unroll
                for (int r = 0; r < 4; ++r)
                    psum[wave][mt * 16 + quad * 4 + r] = p[mt][r];
        }
        __syncthreads();   // psum visible; also drains vmcnt -> next buf ready
        if (tid < SROWS) {
            float ssum = psum[0][tid] + psum[1][tid] + psum[2][tid] + psum[3][tid];
            g[row0 + s * SROWS + tid] = __builtin_amdgcn_rcpf(1.0f + __expf(-ssum));
        }
        __syncthreads();   // protect psum before next subtile
    }
}

// ---------------- stream: windowed sum of g*x over win=64, / windowed g-sum --
// v2: float2-vectorized. Block = 256 thr = 2 groups of 128; each group owns one
// (b, chunk), lane owns 2 d-columns. S += g[t]x[t] - g[t-64]x[t-64]; the
// subtrahend re-read is L2-warm. den fused as scalar recurrence on staged g.
#define TC 128
#define NCHUNK (TT / TC)   // 32

__global__ __launch_bounds__(256) void stream_kernel(
        const float* __restrict__ x, const float* __restrict__ g,
        float* __restrict__ out) {
    __shared__ float gbuf[2][TC + WIN];
    const int grp  = threadIdx.x >> 7;           // 0..1
    const int d2   = threadIdx.x & 127;          // float2 column index
    const int pair = blockIdx.x * 2 + grp;       // (b, chunk) id, 0..1023
    const int b     = pair >> 5;                 // NCHUNK = 32
    const int chunk = pair & (NCHUNK - 1);
    const int t0    = chunk * TC;
    const float2* xb2 = reinterpret_cast<const float2*>(x + (size_t)b * TT * DD);
    const float*  gb  = g + (size_t)b * TT;
    float2* ob2 = reinterpret_cast<float2*>(out + (size_t)b * TT * DD);

    // stage g[t0-64 .. t0+TC-1], zero-padded below 0
    for (int i = d2; i < TC + WIN; i += 128) {
        int s = t0 - WIN + i;
        gbuf[grp][i] = (s >= 0) ? gb[s] : 0.f;
    }
    __syncthreads();

    // halo init over [t0-64, t0-1] (g=0 padding kills clamped loads)
    float2 S = {0.f, 0.f};
    float Sg = 0.f;
#pragma unroll 16
    for (int i = 0; i < WIN; ++i) {
        int s  = t0 - WIN + i;
        int sc = s < 0 ? 0 : s;
        float gv = gbuf[grp][i];
        float2 xv = xb2[(size_t)sc * (DD / 2) + d2];
        S.x += gv * xv.x;
        S.y += gv * xv.y;
        Sg  += gv;
    }

#pragma unroll 8
    for (int tt = 0; tt < TC; ++tt) {
        int t   = t0 + tt;
        int ts  = t - WIN;
        int tsc = ts < 0 ? 0 : ts;
        float gnew = gbuf[grp][WIN + tt];
        float gold = gbuf[grp][tt];
        float2 xn = xb2[(size_t)t   * (DD / 2) + d2];
        float2 xo = xb2[(size_t)tsc * (DD / 2) + d2];
        S.x += gnew * xn.x - gold * xo.x;
        S.y += gnew * xn.y - gold * xo.y;
        Sg  += gnew - gold;
        float r = __builtin_amdgcn_rcpf(Sg);
        float2 o; o.x = S.x * r; o.y = S.y * r;
        ob2[(size_t)t * (DD / 2) + d2] = o;
    }
}

extern "C" void kernel_launch(void* const* d_in, const int* in_sizes, int n_in,
                              void* d_out, int out_size, void* d_ws, size_t ws_size,
                              hipStream_t stream) {
    const float* x  = (const float*)d_in[0];
    const float* Wp = (const float*)d_in[1];
    const float* bp = (const float*)d_in[2];
    const float* Wg = (const float*)d_in[3];
    float* out = (float*)d_out;

    // ws layout: [0,64K) Wp bf16 | [64K, 64K+512K) g
    unsigned short* wpb = (unsigned short*)d_ws;
    float* g = (float*)((char*)d_ws + 65536);

    prep_wp<<<AA * DD / 256, 256, 0, stream>>>(Wp, wpb);
    gate_kernel<<<32 * TT / RTILE, 256, 0, stream>>>(x, wpb, bp, Wg, g);
    stream_kernel<<<32 * NCHUNK / 2, 256, 0, stream>>>(x, g, out);
}